// Round 1
// baseline (973.214 us; speedup 1.0000x reference)
//
#include <hip/hip_runtime.h>
#include <cstdint>

#define B_   1024
#define T_   512
#define D_   64
#define H_   32
#define EPS_ 1e-5f

__device__ __forceinline__ float fast_rcp(float x) { return __builtin_amdgcn_rcpf(x); }
__device__ __forceinline__ float sigm(float x)  { return fast_rcp(1.f + __expf(-x)); }
__device__ __forceinline__ float tanh_(float x) { return 2.f * fast_rcp(1.f + __expf(-2.f * x)) - 1.f; }

// ---------------------------------------------------------------------------
// Kernel 1: pre[b*T+t][g] = BN(x[b,t,:]) . Wih1[g,:] + bih1[g] + bhh1[g]
// 64 rows x 128 gates per 256-thread block. W in LDS [128][65] (padded),
// x tile in LDS with BN fused at load. 8 rows x 4 gates per thread.
// ---------------------------------------------------------------------------
__global__ __launch_bounds__(256) void k_bnxw(
    const float* __restrict__ x,   const float* __restrict__ gam,
    const float* __restrict__ bet, const float* __restrict__ mu,
    const float* __restrict__ var,
    const float* __restrict__ Wih1, const float* __restrict__ bih1,
    const float* __restrict__ bhh1, float* __restrict__ pre)
{
    constexpr int ROWS = 64;
    __shared__ float Ws[128][65];      // row-major, +1 pad
    __shared__ __align__(16) float xs[ROWS][64];
    __shared__ float scs[ROWS], shs[ROWS], bsum[128];

    const int tid = threadIdx.x;
    const int r0  = blockIdx.x * ROWS;

    // per-row BN coefficients (rows of this tile share one batch element; T%64==0)
    if (tid < ROWS) {
        int t = (r0 + tid) & (T_ - 1);
        float inv = rsqrtf(var[t] + EPS_);
        float s = inv * gam[t];
        scs[tid] = s;
        shs[tid] = bet[t] - mu[t] * s;
    }
    if (tid >= 128) bsum[tid - 128] = bih1[tid - 128] + bhh1[tid - 128];

    // load W row-major into padded LDS (coalesced global, conflict-free LDS)
    #pragma unroll
    for (int it = 0; it < 8192 / 256; ++it) {
        int j = tid + it * 256;
        Ws[j >> 6][j & 63] = Wih1[j];
    }
    __syncthreads();   // scs/shs ready

    // load x tile (float4) with BN fused
    const float4* x4 = (const float4*)(x + (size_t)r0 * 64);
    #pragma unroll
    for (int it = 0; it < ROWS * 64 / 4 / 256; ++it) {   // 4 iters
        int j  = tid + it * 256;
        int rr = j >> 4;            // row in tile
        int k4 = j & 15;            // float4 index in row
        float4 v = x4[j];
        float s = scs[rr], sh = shs[rr];
        v.x = v.x * s + sh; v.y = v.y * s + sh;
        v.z = v.z * s + sh; v.w = v.w * s + sh;
        *(float4*)&xs[rr][k4 * 4] = v;
    }
    __syncthreads();

    const int gq = tid & 31;   // gate quad: gates gq*4 .. gq*4+3
    const int rq = tid >> 5;   // row group: rows rq*8 .. rq*8+7

    float acc[8][4];
    #pragma unroll
    for (int r = 0; r < 8; ++r)
        #pragma unroll
        for (int q = 0; q < 4; ++q) acc[r][q] = 0.f;

    #pragma unroll 2
    for (int k = 0; k < 64; ++k) {
        float w0 = Ws[gq * 4 + 0][k];
        float w1 = Ws[gq * 4 + 1][k];
        float w2 = Ws[gq * 4 + 2][k];
        float w3 = Ws[gq * 4 + 3][k];
        #pragma unroll
        for (int rr = 0; rr < 8; ++rr) {
            float xv = xs[rq * 8 + rr][k];      // 2-addr broadcast: free
            acc[rr][0] += xv * w0;
            acc[rr][1] += xv * w1;
            acc[rr][2] += xv * w2;
            acc[rr][3] += xv * w3;
        }
    }

    const float b0 = bsum[gq * 4 + 0], b1 = bsum[gq * 4 + 1];
    const float b2 = bsum[gq * 4 + 2], b3 = bsum[gq * 4 + 3];
    #pragma unroll
    for (int rr = 0; rr < 8; ++rr) {
        int row = r0 + rq * 8 + rr;
        float4 o = make_float4(acc[rr][0] + b0, acc[rr][1] + b1,
                               acc[rr][2] + b2, acc[rr][3] + b3);
        *(float4*)&pre[(size_t)row * 128 + gq * 4] = o;   // coalesced
    }
}

// ---------------------------------------------------------------------------
// Kernel 2: fused 2-layer LSTM recurrence + time-mean + FC.
// One batch element per 128-thread block; thread g owns gate-row g of
// Whh1/Wih2/Whh2 in registers. h/c/z exchanged via tiny LDS buffers.
// 3 barriers per timestep.
// ---------------------------------------------------------------------------
__global__ __launch_bounds__(128) void k_lstm(
    const float* __restrict__ pre,
    const float* __restrict__ Whh1, const float* __restrict__ Wih2,
    const float* __restrict__ Whh2, const float* __restrict__ bih2,
    const float* __restrict__ bhh2, const float* __restrict__ fcW,
    const float* __restrict__ fcb,  float* __restrict__ out)
{
    const int b = blockIdx.x;
    const int g = threadIdx.x;

    __shared__ __align__(16) float h1s[32];
    __shared__ __align__(16) float h2s[32];
    __shared__ float z1b[128];
    __shared__ float z2b[128];

    // gate-row weights in registers (statically indexed only)
    float w1[32], wi2[32], w2[32];
    #pragma unroll
    for (int kk = 0; kk < 8; ++kk) {
        float4 a = *(const float4*)&Whh1[g * 32 + kk * 4];
        w1[kk*4+0] = a.x; w1[kk*4+1] = a.y; w1[kk*4+2] = a.z; w1[kk*4+3] = a.w;
    }
    #pragma unroll
    for (int kk = 0; kk < 8; ++kk) {
        float4 a = *(const float4*)&Wih2[g * 32 + kk * 4];
        wi2[kk*4+0] = a.x; wi2[kk*4+1] = a.y; wi2[kk*4+2] = a.z; wi2[kk*4+3] = a.w;
    }
    #pragma unroll
    for (int kk = 0; kk < 8; ++kk) {
        float4 a = *(const float4*)&Whh2[g * 32 + kk * 4];
        w2[kk*4+0] = a.x; w2[kk*4+1] = a.y; w2[kk*4+2] = a.z; w2[kk*4+3] = a.w;
    }
    const float bias2 = bih2[g] + bhh2[g];

    float c1 = 0.f, c2 = 0.f, hsum = 0.f;
    if (g < 32) { h1s[g] = 0.f; h2s[g] = 0.f; }
    __syncthreads();

    const float* prow = pre + (size_t)b * T_ * 128;
    float zc = prow[g];                       // t=0, prefetched

    for (int t = 0; t < T_; ++t) {
        // prefetch next timestep's input projection (hides HBM/L2 latency)
        float zn = 0.f;
        if (t + 1 < T_) zn = prow[(size_t)(t + 1) * 128 + g];

        // ---- phase 1: z1 = pre + h1_prev . Whh1[g,:]  (2 partial chains)
        float za = zc, zb = 0.f;
        #pragma unroll
        for (int kk = 0; kk < 8; kk += 2) {
            float4 ha = *(const float4*)&h1s[kk * 4];
            float4 hb = *(const float4*)&h1s[kk * 4 + 4];
            za += w1[kk*4+0]*ha.x + w1[kk*4+1]*ha.y + w1[kk*4+2]*ha.z + w1[kk*4+3]*ha.w;
            zb += w1[kk*4+4]*hb.x + w1[kk*4+5]*hb.y + w1[kk*4+6]*hb.z + w1[kk*4+7]*hb.w;
        }
        z1b[g] = za + zb;
        __syncthreads();

        // ---- phase 2: layer-1 cell update (threads 0..31, j = g)
        if (g < 32) {
            float i_ = sigm (z1b[g]);
            float f_ = sigm (z1b[g + 32]);
            float g_ = tanh_(z1b[g + 64]);
            float o_ = sigm (z1b[g + 96]);
            c1 = f_ * c1 + i_ * g_;
            h1s[g] = o_ * tanh_(c1);
        }
        __syncthreads();

        // ---- phase 3: z2 = bias2 + h1 . Wih2[g,:] + h2_prev . Whh2[g,:]
        float s0 = bias2, s1 = 0.f, s2 = 0.f, s3 = 0.f;
        #pragma unroll
        for (int kk = 0; kk < 8; kk += 2) {
            float4 ha = *(const float4*)&h1s[kk * 4];
            float4 hb = *(const float4*)&h1s[kk * 4 + 4];
            s0 += wi2[kk*4+0]*ha.x + wi2[kk*4+1]*ha.y + wi2[kk*4+2]*ha.z + wi2[kk*4+3]*ha.w;
            s1 += wi2[kk*4+4]*hb.x + wi2[kk*4+5]*hb.y + wi2[kk*4+6]*hb.z + wi2[kk*4+7]*hb.w;
        }
        #pragma unroll
        for (int kk = 0; kk < 8; kk += 2) {
            float4 ha = *(const float4*)&h2s[kk * 4];
            float4 hb = *(const float4*)&h2s[kk * 4 + 4];
            s2 += w2[kk*4+0]*ha.x + w2[kk*4+1]*ha.y + w2[kk*4+2]*ha.z + w2[kk*4+3]*ha.w;
            s3 += w2[kk*4+4]*hb.x + w2[kk*4+5]*hb.y + w2[kk*4+6]*hb.z + w2[kk*4+7]*hb.w;
        }
        z2b[g] = (s0 + s1) + (s2 + s3);
        __syncthreads();

        // ---- phase 4: layer-2 cell update + time pooling (no trailing
        // barrier needed: next iteration's barriers cover the hazards)
        if (g < 32) {
            float i_ = sigm (z2b[g]);
            float f_ = sigm (z2b[g + 32]);
            float g_ = tanh_(z2b[g + 64]);
            float o_ = sigm (z2b[g + 96]);
            c2 = f_ * c2 + i_ * g_;
            float h2 = o_ * tanh_(c2);
            h2s[g] = h2;
            hsum += h2;
        }
        zc = zn;
    }

    // ---- epilogue: pooled = hsum/T ; out = pooled @ fcW^T + fcb
    __syncthreads();
    if (g < 32) z1b[g] = hsum * (1.f / T_);
    __syncthreads();
    if (g < 2) {
        float acc = fcb[g];
        #pragma unroll
        for (int j = 0; j < 32; ++j) acc += z1b[j] * fcW[g * 32 + j];
        out[b * 2 + g] = acc;
    }
}

// ---------------------------------------------------------------------------
extern "C" void kernel_launch(void* const* d_in, const int* in_sizes, int n_in,
                              void* d_out, int out_size, void* d_ws, size_t ws_size,
                              hipStream_t stream)
{
    const float* x    = (const float*)d_in[0];
    const float* gam  = (const float*)d_in[1];
    const float* bet  = (const float*)d_in[2];
    const float* mu   = (const float*)d_in[3];
    const float* var  = (const float*)d_in[4];
    const float* Wih1 = (const float*)d_in[5];
    const float* Whh1 = (const float*)d_in[6];
    const float* bih1 = (const float*)d_in[7];
    const float* bhh1 = (const float*)d_in[8];
    const float* Wih2 = (const float*)d_in[9];
    const float* Whh2 = (const float*)d_in[10];
    const float* bih2 = (const float*)d_in[11];
    const float* bhh2 = (const float*)d_in[12];
    const float* fcW  = (const float*)d_in[13];
    const float* fcb  = (const float*)d_in[14];
    float*       out  = (float*)d_out;

    float* pre = (float*)d_ws;   // needs B*T*128*4 = 256 MB scratch

    k_bnxw<<<dim3(B_ * T_ / 64), 256, 0, stream>>>(
        x, gam, bet, mu, var, Wih1, bih1, bhh1, pre);
    k_lstm<<<dim3(B_), 128, 0, stream>>>(
        pre, Whh1, Wih2, Whh2, bih2, bhh2, fcW, fcb, out);
}

// Round 2
// 850.410 us; speedup vs baseline: 1.1444x; 1.1444x over previous
//
#include <hip/hip_runtime.h>
#include <cstdint>

#define B_   1024
#define T_   512
#define D_   64
#define H_   32
#define EPS_ 1e-5f

__device__ __forceinline__ float fast_rcp(float x) { return __builtin_amdgcn_rcpf(x); }
__device__ __forceinline__ float sigm(float x)  { return fast_rcp(1.f + __expf(-x)); }
__device__ __forceinline__ float tanh_(float x) { return 2.f * fast_rcp(1.f + __expf(-2.f * x)) - 1.f; }

// ---------------------------------------------------------------------------
// Fully fused: BN + xw-projection + 2-layer LSTM recurrence + time-mean + FC.
// One batch element per 256-thread block (4 waves).
//
// Gate->wave mapping: wave w owns gates {w*8 + jj + 32*q : jj in [0,8), q in
// [0,4)} and cells j in [w*8, w*8+8). Hence each cell's 4 gate pre-acts are
// produced INSIDE one wave -> z exchange is wave-local LDS (no barrier).
// Cross-wave traffic is only h1/h2 (32 floats each), double-buffered by t
// parity -> exactly ONE __syncthreads per timestep.
//
// Thread (lane l): m = l>>1 (gate slot), half = l&1 (K-split half). Each
// thread holds 80 weight floats in registers:
//   wx[32]  = Wih1[g][half*32 .. +32)
//   w1h[16] = Whh1[g][half*16 .. +16)
//   wi2h[16]= Wih2[g][half*16 .. +16)
//   w2h[16] = Whh2[g][half*16 .. +16)
// Halves combined with one __shfl_xor(za,1).
// ---------------------------------------------------------------------------
__global__ __launch_bounds__(256, 4) void k_fused(
    const float* __restrict__ x,
    const float* __restrict__ gam, const float* __restrict__ bet,
    const float* __restrict__ mu,  const float* __restrict__ var,
    const float* __restrict__ Wih1, const float* __restrict__ Whh1,
    const float* __restrict__ bih1, const float* __restrict__ bhh1,
    const float* __restrict__ Wih2, const float* __restrict__ Whh2,
    const float* __restrict__ bih2, const float* __restrict__ bhh2,
    const float* __restrict__ fcW,  const float* __restrict__ fcb,
    float* __restrict__ out)
{
    __shared__ float scl[T_], shl[T_];              // BN scale/shift per t
    __shared__ __align__(16) float xs[2][D_];       // staged BN(x_t), dbuf
    __shared__ __align__(16) float h1s[2][H_];      // h1, dbuf by t parity
    __shared__ __align__(16) float h2s[2][H_];      // h2, dbuf by t parity
    __shared__ float zw[4][32];                     // per-wave z scratch
    __shared__ float pool[H_];

    const int tid  = threadIdx.x;
    const int w    = tid >> 6;        // wave id 0..3
    const int l    = tid & 63;        // lane
    const int m    = l >> 1;          // gate slot 0..31 within wave
    const int half = l & 1;           // K-split half
    const int jj   = m & 7;           // cell sub-index
    const int q    = m >> 3;          // gate group (i,f,g,o)
    const int g    = w * 8 + jj + 32 * q;   // global gate row 0..127
    const int b    = blockIdx.x;

    // ---- BN coefficient tables (per t; BN is over the T axis) ----
    for (int t0 = tid; t0 < T_; t0 += 256) {
        float s = rsqrtf(var[t0] + EPS_) * gam[t0];
        scl[t0] = s;
        shl[t0] = bet[t0] - mu[t0] * s;
    }
    if (tid < H_) { h1s[0][tid] = 0.f; h2s[0][tid] = 0.f; }

    // ---- weights into registers (statically indexed, fully unrolled) ----
    float wx[32], w1h[16], wi2h[16], w2h[16];
    {
        const float4* p4 = (const float4*)(Wih1 + g * 64 + half * 32);
        #pragma unroll
        for (int i = 0; i < 8; ++i) {
            float4 v = p4[i];
            wx[4*i] = v.x; wx[4*i+1] = v.y; wx[4*i+2] = v.z; wx[4*i+3] = v.w;
        }
    }
    {
        const float4* p4 = (const float4*)(Whh1 + g * 32 + half * 16);
        #pragma unroll
        for (int i = 0; i < 4; ++i) {
            float4 v = p4[i];
            w1h[4*i] = v.x; w1h[4*i+1] = v.y; w1h[4*i+2] = v.z; w1h[4*i+3] = v.w;
        }
    }
    {
        const float4* p4 = (const float4*)(Wih2 + g * 32 + half * 16);
        #pragma unroll
        for (int i = 0; i < 4; ++i) {
            float4 v = p4[i];
            wi2h[4*i] = v.x; wi2h[4*i+1] = v.y; wi2h[4*i+2] = v.z; wi2h[4*i+3] = v.w;
        }
    }
    {
        const float4* p4 = (const float4*)(Whh2 + g * 32 + half * 16);
        #pragma unroll
        for (int i = 0; i < 4; ++i) {
            float4 v = p4[i];
            w2h[4*i] = v.x; w2h[4*i+1] = v.y; w2h[4*i+2] = v.z; w2h[4*i+3] = v.w;
        }
    }
    const float bias1 = (half == 0) ? (bih1[g] + bhh1[g]) : 0.f;
    const float bias2 = (half == 0) ? (bih2[g] + bhh2[g]) : 0.f;

    __syncthreads();                       // tables + h zero visible

    // ---- stage BN(x_0) ----
    const float* xrow = x + (size_t)b * T_ * D_;
    if (l < 16) {
        float xv = xrow[w * 16 + l];
        xs[0][w * 16 + l] = xv * scl[0] + shl[0];
    }
    __syncthreads();

    float c1 = 0.f, c2 = 0.f, hsum = 0.f;
    const bool wrH = (half == 0) && (q == 0);   // lanes that publish h[w*8+jj]

    for (int t = 0; t < T_; ++t) {
        const int p = t & 1;

        // -- prefetch raw x(t+1) (BN applied at write) --
        float xnext = 0.f;
        if (l < 16 && t + 1 < T_)
            xnext = xrow[(t + 1) * 64 + w * 16 + l];

        // -- phase 1: z1(g) = bias1 + BN(x_t).Wih1[g] + h1.Whh1[g] --
        {
            const float* xp  = &xs[p][half * 32];
            const float* h1p = &h1s[p][half * 16];
            float a0 = bias1, a1 = 0.f, a2 = 0.f, a3 = 0.f;
            #pragma unroll
            for (int i = 0; i < 8; ++i) {
                float4 v = *(const float4*)(xp + 4 * i);
                a0 += wx[4*i]   * v.x; a1 += wx[4*i+1] * v.y;
                a2 += wx[4*i+2] * v.z; a3 += wx[4*i+3] * v.w;
            }
            #pragma unroll
            for (int i = 0; i < 4; ++i) {
                float4 v = *(const float4*)(h1p + 4 * i);
                a0 += w1h[4*i]   * v.x; a1 += w1h[4*i+1] * v.y;
                a2 += w1h[4*i+2] * v.z; a3 += w1h[4*i+3] * v.w;
            }
            float za = (a0 + a1) + (a2 + a3);
            za += __shfl_xor(za, 1);       // combine K-halves (partner lane)
            if (half == 0) zw[w][m] = za;  // wave-local publish
        }

        // -- phase 2: layer-1 cell update (replicated across 8 lanes/cell) --
        {
            float zi = zw[w][jj],      zf = zw[w][jj + 8];
            float zg = zw[w][jj + 16], zo = zw[w][jj + 24];
            float i_ = sigm(zi), f_ = sigm(zf), g_ = tanh_(zg), o_ = sigm(zo);
            c1 = f_ * c1 + i_ * g_;
            float h1 = o_ * tanh_(c1);
            if (wrH) h1s[1 - p][w * 8 + jj] = h1;
        }

        // -- stage BN(x_{t+1}) into the other buffer --
        if (l < 16 && t + 1 < T_)
            xs[1 - p][w * 16 + l] = xnext * scl[t + 1] + shl[t + 1];

        __syncthreads();   // the ONLY barrier: publishes h1(t) (+x stage)

        // -- phase 3: z2(g) = bias2 + h1(t).Wih2[g] + h2(t-1).Whh2[g] --
        {
            const float* h1n = &h1s[1 - p][half * 16];
            const float* h2p = &h2s[p][half * 16];
            float s0 = bias2, s1 = 0.f, s2 = 0.f, s3 = 0.f;
            #pragma unroll
            for (int i = 0; i < 4; ++i) {
                float4 v = *(const float4*)(h1n + 4 * i);
                s0 += wi2h[4*i]   * v.x; s1 += wi2h[4*i+1] * v.y;
                s2 += wi2h[4*i+2] * v.z; s3 += wi2h[4*i+3] * v.w;
            }
            #pragma unroll
            for (int i = 0; i < 4; ++i) {
                float4 v = *(const float4*)(h2p + 4 * i);
                s0 += w2h[4*i]   * v.x; s1 += w2h[4*i+1] * v.y;
                s2 += w2h[4*i+2] * v.z; s3 += w2h[4*i+3] * v.w;
            }
            float zb = (s0 + s1) + (s2 + s3);
            zb += __shfl_xor(zb, 1);
            if (half == 0) zw[w][m] = zb;  // reuse wave-local scratch
        }

        // -- phase 4: layer-2 cell update + time pooling --
        {
            float zi = zw[w][jj],      zf = zw[w][jj + 8];
            float zg = zw[w][jj + 16], zo = zw[w][jj + 24];
            float i_ = sigm(zi), f_ = sigm(zf), g_ = tanh_(zg), o_ = sigm(zo);
            c2 = f_ * c2 + i_ * g_;
            float h2v = o_ * tanh_(c2);
            hsum += h2v;                   // replicated; one replica published
            if (wrH) h2s[1 - p][w * 8 + jj] = h2v;
        }
        // no trailing barrier: next step's barrier covers h2/zw hazards
    }

    // ---- epilogue: pooled = hsum/T ; out = pooled @ fcW^T + fcb ----
    if (wrH) pool[w * 8 + jj] = hsum * (1.f / T_);
    __syncthreads();
    if (tid < 2) {
        float acc = fcb[tid];
        #pragma unroll
        for (int j = 0; j < 32; ++j) acc += pool[j] * fcW[tid * 32 + j];
        out[b * 2 + tid] = acc;
    }
}

// ---------------------------------------------------------------------------
extern "C" void kernel_launch(void* const* d_in, const int* in_sizes, int n_in,
                              void* d_out, int out_size, void* d_ws, size_t ws_size,
                              hipStream_t stream)
{
    const float* x    = (const float*)d_in[0];
    const float* gam  = (const float*)d_in[1];
    const float* bet  = (const float*)d_in[2];
    const float* mu   = (const float*)d_in[3];
    const float* var  = (const float*)d_in[4];
    const float* Wih1 = (const float*)d_in[5];
    const float* Whh1 = (const float*)d_in[6];
    const float* bih1 = (const float*)d_in[7];
    const float* bhh1 = (const float*)d_in[8];
    const float* Wih2 = (const float*)d_in[9];
    const float* Whh2 = (const float*)d_in[10];
    const float* bih2 = (const float*)d_in[11];
    const float* bhh2 = (const float*)d_in[12];
    const float* fcW  = (const float*)d_in[13];
    const float* fcb  = (const float*)d_in[14];
    float*       out  = (float*)d_out;

    k_fused<<<dim3(B_), 256, 0, stream>>>(
        x, gam, bet, mu, var, Wih1, Whh1, bih1, bhh1,
        Wih2, Whh2, bih2, bhh2, fcW, fcb, out);
}

// Round 3
// 747.189 us; speedup vs baseline: 1.3025x; 1.1381x over previous
//
#include <hip/hip_runtime.h>
#include <cstdint>

#define B_   1024
#define T_   512
#define D_   64
#define H_   32
#define EPS_ 1e-5f

__device__ __forceinline__ float fast_rcp(float x) { return __builtin_amdgcn_rcpf(x); }

// ---------------------------------------------------------------------------
// Kernel 1: pre[row][g] = BN(x[row,:]) . Wih1[g,:] + bih1[g] + bhh1[g]
// row = b*T + t. 64 rows x 128 gates per 256-thread block.
// W transposed in LDS Wt[k][g] (stride 132 -> 16B-aligned b128 reads whose
// 32 lane-chunks tile the banks), x tile BN-fused at stage time.
// Thread = (gq = tid&31 -> gates gq*4..+3, rq = tid>>5 -> rows rq*8..+7).
// Inner loop: per k-quad 12x ds_read_b128 + 128 FMA (FMA-issue-bound).
// ---------------------------------------------------------------------------
__global__ __launch_bounds__(256, 3) void k_bnxw(
    const float* __restrict__ x,   const float* __restrict__ gam,
    const float* __restrict__ bet, const float* __restrict__ mu,
    const float* __restrict__ var,
    const float* __restrict__ Wih1, const float* __restrict__ bih1,
    const float* __restrict__ bhh1, float* __restrict__ pre)
{
    __shared__ __align__(16) float Wt[64][132];   // transposed, padded
    __shared__ __align__(16) float xs[64][64];
    __shared__ float scs[64], shs[64], bsum[128];

    const int tid = threadIdx.x;
    const int r0  = blockIdx.x * 64;

    if (tid < 64) {
        int t = (r0 + tid) & (T_ - 1);
        float s = rsqrtf(var[t] + EPS_) * gam[t];
        scs[tid] = s;
        shs[tid] = bet[t] - mu[t] * s;
    }
    if (tid >= 128) bsum[tid - 128] = bih1[tid - 128] + bhh1[tid - 128];

    // stage W transposed: coalesced float4 global reads along k, 4x ds_write
    #pragma unroll
    for (int it = 0; it < 8; ++it) {
        int idx4 = tid + it * 256;            // float4 index into Wih1 (2048)
        float4 v = ((const float4*)Wih1)[idx4];
        int g  = idx4 >> 4;                   // 16 float4 per 64-wide row
        int k0 = (idx4 & 15) * 4;
        Wt[k0 + 0][g] = v.x; Wt[k0 + 1][g] = v.y;
        Wt[k0 + 2][g] = v.z; Wt[k0 + 3][g] = v.w;
    }
    __syncthreads();                          // scs/shs ready

    const float4* x4 = (const float4*)(x + (size_t)r0 * 64);
    #pragma unroll
    for (int it = 0; it < 4; ++it) {
        int j  = tid + it * 256;
        int rr = j >> 4;
        int k4 = j & 15;
        float4 v = x4[j];
        float s = scs[rr], sh = shs[rr];
        v.x = v.x * s + sh; v.y = v.y * s + sh;
        v.z = v.z * s + sh; v.w = v.w * s + sh;
        *(float4*)&xs[rr][k4 * 4] = v;
    }
    __syncthreads();

    const int gq = tid & 31;
    const int rq = tid >> 5;

    float acc[8][4];
    #pragma unroll
    for (int r = 0; r < 8; ++r)
        #pragma unroll
        for (int q = 0; q < 4; ++q) acc[r][q] = 0.f;

    #pragma unroll 4
    for (int kq = 0; kq < 16; ++kq) {
        float4 wv[4];
        #pragma unroll
        for (int kk = 0; kk < 4; ++kk)
            wv[kk] = *(const float4*)&Wt[kq * 4 + kk][gq * 4];
        #pragma unroll
        for (int rr = 0; rr < 8; ++rr) {
            float4 xv = *(const float4*)&xs[rq * 8 + rr][kq * 4];
            acc[rr][0] += xv.x * wv[0].x + xv.y * wv[1].x + xv.z * wv[2].x + xv.w * wv[3].x;
            acc[rr][1] += xv.x * wv[0].y + xv.y * wv[1].y + xv.z * wv[2].y + xv.w * wv[3].y;
            acc[rr][2] += xv.x * wv[0].z + xv.y * wv[1].z + xv.z * wv[2].z + xv.w * wv[3].z;
            acc[rr][3] += xv.x * wv[0].w + xv.y * wv[1].w + xv.z * wv[2].w + xv.w * wv[3].w;
        }
    }

    const float b0 = bsum[gq * 4 + 0], b1 = bsum[gq * 4 + 1];
    const float b2 = bsum[gq * 4 + 2], b3 = bsum[gq * 4 + 3];
    #pragma unroll
    for (int rr = 0; rr < 8; ++rr) {
        int row = r0 + rq * 8 + rr;
        float4 o = make_float4(acc[rr][0] + b0, acc[rr][1] + b1,
                               acc[rr][2] + b2, acc[rr][3] + b3);
        *(float4*)&pre[(size_t)row * 128 + gq * 4] = o;
    }
}

// ---------------------------------------------------------------------------
// Kernel 2: 2-layer LSTM recurrence + time-mean + FC, reading pre1.
// One batch element per 256-thread block (4 waves, exactly 4 blocks/CU).
// Wave w owns gates {w*8+jj+32q}; lane = (m = l>>1 gate slot, half = l&1
// K-split). 48 weight floats/thread PINNED in VGPRs via asm. Cell updates
// de-replicated: one exp+rcp per lane covers all gate nonlinearities
// (tanh(x) = 2*sigm(2x)-1 with per-lane a,b), redistribution via wave-local
// LDS. ONE __syncthreads per timestep.
// ---------------------------------------------------------------------------
__global__ __launch_bounds__(256, 4) void k_rec(
    const float* __restrict__ pre,
    const float* __restrict__ Whh1, const float* __restrict__ Wih2,
    const float* __restrict__ Whh2, const float* __restrict__ bih2,
    const float* __restrict__ bhh2, const float* __restrict__ fcW,
    const float* __restrict__ fcb,  float* __restrict__ out)
{
    __shared__ __align__(16) float h1s[2][H_];
    __shared__ __align__(16) float h2s[2][H_];
    __shared__ float zw[4][32];
    __shared__ float pool[H_];

    const int tid  = threadIdx.x;
    const int w    = tid >> 6;
    const int l    = tid & 63;
    const int m    = l >> 1;
    const int half = l & 1;
    const int jj   = m & 7;
    const int q    = m >> 3;
    const int g    = w * 8 + jj + 32 * q;
    const int b    = blockIdx.x;

    if (tid < H_) { h1s[0][tid] = 0.f; h2s[0][tid] = 0.f; }

    // ---- 48 weight floats into registers, PINNED (no remat possible) ----
    float w1h[16], wi2h[16], w2h[16];
    {
        const float4* p4 = (const float4*)(Whh1 + g * 32 + half * 16);
        #pragma unroll
        for (int i = 0; i < 4; ++i) {
            float4 v = p4[i];
            w1h[4*i] = v.x; w1h[4*i+1] = v.y; w1h[4*i+2] = v.z; w1h[4*i+3] = v.w;
        }
    }
    {
        const float4* p4 = (const float4*)(Wih2 + g * 32 + half * 16);
        #pragma unroll
        for (int i = 0; i < 4; ++i) {
            float4 v = p4[i];
            wi2h[4*i] = v.x; wi2h[4*i+1] = v.y; wi2h[4*i+2] = v.z; wi2h[4*i+3] = v.w;
        }
    }
    {
        const float4* p4 = (const float4*)(Whh2 + g * 32 + half * 16);
        #pragma unroll
        for (int i = 0; i < 4; ++i) {
            float4 v = p4[i];
            w2h[4*i] = v.x; w2h[4*i+1] = v.y; w2h[4*i+2] = v.z; w2h[4*i+3] = v.w;
        }
    }
    #pragma unroll
    for (int i = 0; i < 16; ++i) {
        asm volatile("" : "+v"(w1h[i]));
        asm volatile("" : "+v"(wi2h[i]));
        asm volatile("" : "+v"(w2h[i]));
    }
    float bias1 = (half == 0) ? 0.f : 0.f;   // layer-1 bias folded into pre
    float bias2 = (half == 0) ? (bih2[g] + bhh2[g]) : 0.f;
    asm volatile("" : "+v"(bias2));
    (void)bias1;

    // per-lane nonlinearity constants: q==2 is the tanh gate
    const float act_a = (q == 2) ? 2.f : 1.f;
    const float act_b = (q == 2) ? -1.f : 0.f;

    __syncthreads();

    const float* prow = pre + (size_t)b * T_ * 128;
    float zc = prow[g];                      // t=0 input projection
    float c1 = 0.f, c2 = 0.f, hsum = 0.f;
    const bool wrH = (half == 0) && (q == 0);

    for (int t = 0; t < T_; ++t) {
        const int p = t & 1;

        // prefetch next step's projection (covers HBM/L2/L3 latency)
        float zn = 0.f;
        if (t + 1 < T_) zn = prow[(size_t)(t + 1) * 128 + g];

        // ---- phase 1: z1 = pre + h1(t-1) . Whh1[g, half-K] ----
        {
            const float* h1p = &h1s[p][half * 16];
            float a0 = (half == 0) ? zc : 0.f;
            float a1 = 0.f, a2 = 0.f, a3 = 0.f;
            #pragma unroll
            for (int i = 0; i < 4; ++i) {
                float4 v = *(const float4*)(h1p + 4 * i);
                a0 += w1h[4*i]   * v.x; a1 += w1h[4*i+1] * v.y;
                a2 += w1h[4*i+2] * v.z; a3 += w1h[4*i+3] * v.w;
            }
            float za = (a0 + a1) + (a2 + a3);
            za += __shfl_xor(za, 1);         // combine K-halves

            // ---- phase 2: de-replicated nonlinearity + cell-1 update ----
            float u = act_a * za;
            float s = fast_rcp(1.f + __expf(-u));
            float act = fmaf(act_a, s, act_b);
            if (half == 0) zw[w][m] = act;
            float i_ = zw[w][jj],      f_ = zw[w][jj + 8];
            float g_ = zw[w][jj + 16], o_ = zw[w][jj + 24];
            c1 = f_ * c1 + i_ * g_;
            float th = fmaf(2.f, fast_rcp(1.f + __expf(-2.f * c1)), -1.f);
            float h1 = o_ * th;
            if (wrH) h1s[1 - p][w * 8 + jj] = h1;
        }

        __syncthreads();   // the ONLY barrier: publishes h1(t)

        // ---- phase 3: z2 = bias2 + h1(t).Wih2 + h2(t-1).Whh2 ----
        {
            const float* h1n = &h1s[1 - p][half * 16];
            const float* h2p = &h2s[p][half * 16];
            float s0 = bias2, s1 = 0.f, s2 = 0.f, s3 = 0.f;
            #pragma unroll
            for (int i = 0; i < 4; ++i) {
                float4 v = *(const float4*)(h1n + 4 * i);
                s0 += wi2h[4*i]   * v.x; s1 += wi2h[4*i+1] * v.y;
                s2 += wi2h[4*i+2] * v.z; s3 += wi2h[4*i+3] * v.w;
            }
            #pragma unroll
            for (int i = 0; i < 4; ++i) {
                float4 v = *(const float4*)(h2p + 4 * i);
                s0 += w2h[4*i]   * v.x; s1 += w2h[4*i+1] * v.y;
                s2 += w2h[4*i+2] * v.z; s3 += w2h[4*i+3] * v.w;
            }
            float zb = (s0 + s1) + (s2 + s3);
            zb += __shfl_xor(zb, 1);

            // ---- phase 4: nonlinearity + cell-2 update + pooling ----
            float u = act_a * zb;
            float s = fast_rcp(1.f + __expf(-u));
            float act = fmaf(act_a, s, act_b);
            if (half == 0) zw[w][m] = act;
            float i_ = zw[w][jj],      f_ = zw[w][jj + 8];
            float g_ = zw[w][jj + 16], o_ = zw[w][jj + 24];
            c2 = f_ * c2 + i_ * g_;
            float th = fmaf(2.f, fast_rcp(1.f + __expf(-2.f * c2)), -1.f);
            float h2v = o_ * th;
            hsum += h2v;
            if (wrH) h2s[1 - p][w * 8 + jj] = h2v;
        }
        zc = zn;
        // no trailing barrier: next step's barrier covers h2/zw hazards
    }

    // ---- epilogue ----
    if (wrH) pool[w * 8 + jj] = hsum * (1.f / T_);
    __syncthreads();
    if (tid < 2) {
        float acc = fcb[tid];
        #pragma unroll
        for (int j = 0; j < 32; ++j) acc += pool[j] * fcW[tid * 32 + j];
        out[b * 2 + tid] = acc;
    }
}

// ---------------------------------------------------------------------------
extern "C" void kernel_launch(void* const* d_in, const int* in_sizes, int n_in,
                              void* d_out, int out_size, void* d_ws, size_t ws_size,
                              hipStream_t stream)
{
    const float* x    = (const float*)d_in[0];
    const float* gam  = (const float*)d_in[1];
    const float* bet  = (const float*)d_in[2];
    const float* mu   = (const float*)d_in[3];
    const float* var  = (const float*)d_in[4];
    const float* Wih1 = (const float*)d_in[5];
    const float* Whh1 = (const float*)d_in[6];
    const float* bih1 = (const float*)d_in[7];
    const float* bhh1 = (const float*)d_in[8];
    const float* Wih2 = (const float*)d_in[9];
    const float* Whh2 = (const float*)d_in[10];
    const float* bih2 = (const float*)d_in[11];
    const float* bhh2 = (const float*)d_in[12];
    const float* fcW  = (const float*)d_in[13];
    const float* fcb  = (const float*)d_in[14];
    float*       out  = (float*)d_out;

    float* pre = (float*)d_ws;   // B*T*128*4 = 256 MB scratch (validated R0)

    k_bnxw<<<dim3(B_ * T_ / 64), 256, 0, stream>>>(
        x, gam, bet, mu, var, Wih1, bih1, bhh1, pre);
    k_rec<<<dim3(B_), 256, 0, stream>>>(
        pre, Whh1, Wih2, Whh2, bih2, bhh2, fcW, fcb, out);
}

// Round 5
// 639.147 us; speedup vs baseline: 1.5227x; 1.1690x over previous
//
#include <hip/hip_runtime.h>
#include <cstdint>

#define B_   1024
#define T_   512
#define D_   64
#define H_   32
#define EPS_ 1e-5f

__device__ __forceinline__ float rcp_(float x) { return __builtin_amdgcn_rcpf(x); }

// quad_perm DPP move (xor1=0xB1, xor2=0x4E, xor3=0x1B)
template<int CTRL>
__device__ __forceinline__ float qperm(float x) {
    int i = __builtin_bit_cast(int, x);
    i = __builtin_amdgcn_mov_dpp(i, CTRL, 0xF, 0xF, true);
    return __builtin_bit_cast(float, i);
}

// ---------------------------------------------------------------------------
// Kernel 1: pre[row][g] = BN(x[row,:]) . Wih1[g,:] + bih1[g] + bhh1[g]
// 128 rows x 128 gates per 256-thread block; 16 rows x 4 gates per thread.
// LDS: Wt[64][132] transposed (b128 reads conflict-free), xs[128][64] BN-fused.
// Per kq: 20 b128 reads per 256 FMA -> VALU-issue-bound.
// ---------------------------------------------------------------------------
__global__ __launch_bounds__(256, 2) void k_bnxw(
    const float* __restrict__ x,   const float* __restrict__ gam,
    const float* __restrict__ bet, const float* __restrict__ mu,
    const float* __restrict__ var,
    const float* __restrict__ Wih1, const float* __restrict__ bih1,
    const float* __restrict__ bhh1, float* __restrict__ pre)
{
    __shared__ __align__(16) float Wt[64][132];
    __shared__ __align__(16) float xs[128][64];
    __shared__ float scs[128], shs[128], bsum[128];

    const int tid = threadIdx.x;
    const int r0  = blockIdx.x * 128;

    if (tid < 128) {
        int t = (r0 + tid) & (T_ - 1);
        float s = rsqrtf(var[t] + EPS_) * gam[t];
        scs[tid] = s;
        shs[tid] = bet[t] - mu[t] * s;
    } else {
        bsum[tid - 128] = bih1[tid - 128] + bhh1[tid - 128];
    }

    // stage W transposed (one-time; coalesced global float4)
    #pragma unroll
    for (int it = 0; it < 8; ++it) {
        int idx4 = tid + it * 256;            // 2048 float4 total
        float4 v = ((const float4*)Wih1)[idx4];
        int gg = idx4 >> 4;
        int k0 = (idx4 & 15) * 4;
        Wt[k0 + 0][gg] = v.x; Wt[k0 + 1][gg] = v.y;
        Wt[k0 + 2][gg] = v.z; Wt[k0 + 3][gg] = v.w;
    }
    __syncthreads();                          // scs/shs ready

    // stage x with BN fused (coalesced float4)
    const float4* x4 = (const float4*)(x + (size_t)r0 * 64);
    #pragma unroll
    for (int it = 0; it < 8; ++it) {
        int j  = tid + it * 256;              // 2048 float4 total
        int rr = j >> 4;
        int k4 = j & 15;
        float4 v = x4[j];
        float s = scs[rr], sh = shs[rr];
        v.x = fmaf(v.x, s, sh); v.y = fmaf(v.y, s, sh);
        v.z = fmaf(v.z, s, sh); v.w = fmaf(v.w, s, sh);
        *(float4*)&xs[rr][k4 * 4] = v;
    }
    __syncthreads();

    const int gq = tid & 31;    // gates gq*4 .. +3
    const int rq = tid >> 5;    // rows rq*16 .. +15

    float acc[16][4];
    #pragma unroll
    for (int r = 0; r < 16; ++r)
        #pragma unroll
        for (int c = 0; c < 4; ++c) acc[r][c] = 0.f;

    #pragma unroll 2
    for (int kq = 0; kq < 16; ++kq) {
        float4 wv0 = *(const float4*)&Wt[kq * 4 + 0][gq * 4];
        float4 wv1 = *(const float4*)&Wt[kq * 4 + 1][gq * 4];
        float4 wv2 = *(const float4*)&Wt[kq * 4 + 2][gq * 4];
        float4 wv3 = *(const float4*)&Wt[kq * 4 + 3][gq * 4];
        #pragma unroll
        for (int rr = 0; rr < 16; ++rr) {
            float4 xv = *(const float4*)&xs[rq * 16 + rr][kq * 4];
            acc[rr][0] = fmaf(xv.x, wv0.x, acc[rr][0]);
            acc[rr][0] = fmaf(xv.y, wv1.x, acc[rr][0]);
            acc[rr][0] = fmaf(xv.z, wv2.x, acc[rr][0]);
            acc[rr][0] = fmaf(xv.w, wv3.x, acc[rr][0]);
            acc[rr][1] = fmaf(xv.x, wv0.y, acc[rr][1]);
            acc[rr][1] = fmaf(xv.y, wv1.y, acc[rr][1]);
            acc[rr][1] = fmaf(xv.z, wv2.y, acc[rr][1]);
            acc[rr][1] = fmaf(xv.w, wv3.y, acc[rr][1]);
            acc[rr][2] = fmaf(xv.x, wv0.z, acc[rr][2]);
            acc[rr][2] = fmaf(xv.y, wv1.z, acc[rr][2]);
            acc[rr][2] = fmaf(xv.z, wv2.z, acc[rr][2]);
            acc[rr][2] = fmaf(xv.w, wv3.z, acc[rr][2]);
            acc[rr][3] = fmaf(xv.x, wv0.w, acc[rr][3]);
            acc[rr][3] = fmaf(xv.y, wv1.w, acc[rr][3]);
            acc[rr][3] = fmaf(xv.z, wv2.w, acc[rr][3]);
            acc[rr][3] = fmaf(xv.w, wv3.w, acc[rr][3]);
        }
    }

    const float b0 = bsum[gq * 4 + 0], b1 = bsum[gq * 4 + 1];
    const float b2 = bsum[gq * 4 + 2], b3 = bsum[gq * 4 + 3];
    #pragma unroll
    for (int rr = 0; rr < 16; ++rr) {
        int row = r0 + rq * 16 + rr;
        float4 o = make_float4(acc[rr][0] + b0, acc[rr][1] + b1,
                               acc[rr][2] + b2, acc[rr][3] + b3);
        *(float4*)&pre[(size_t)row * 128 + gq * 4] = o;
    }
}

// ---------------------------------------------------------------------------
// Kernel 2: 2-layer LSTM recurrence + time-mean + FC.
// 128 threads (2 waves) per batch element. Lane l: cell jj=l>>2 (wave-local),
// gate-group q=l&3, gate g = w*16 + jj + 32q. A cell's 4 gates live in one
// DPP QUAD -> gate exchange is 3 quad_perm moves, no LDS, no selects (only
// q==0 lanes produce valid cell state; others compute discarded values).
// 96 weight floats/thread in VGPRs (256-reg budget). ONE barrier per step.
// ---------------------------------------------------------------------------
__global__ __launch_bounds__(128, 2) void k_rec(
    const float* __restrict__ pre,
    const float* __restrict__ Whh1, const float* __restrict__ Wih2,
    const float* __restrict__ Whh2, const float* __restrict__ bih2,
    const float* __restrict__ bhh2, const float* __restrict__ fcW,
    const float* __restrict__ fcb,  float* __restrict__ out)
{
    __shared__ __align__(16) float h1s[2][H_];
    __shared__ __align__(16) float h2s[2][H_];
    __shared__ float pool[H_];

    const int tid  = threadIdx.x;
    const int w    = tid >> 6;          // wave 0..1
    const int l    = tid & 63;
    const int jj   = l >> 2;            // cell sub-index 0..15
    const int q    = l & 3;             // gate group (i,f,g,o)
    const int g    = w * 16 + jj + 32 * q;
    const int cell = w * 16 + jj;
    const bool q0  = (q == 0);
    const int b    = blockIdx.x;

    if (tid < H_) { h1s[0][tid] = 0.f; h2s[0][tid] = 0.f; }

    // ---- 96 weight floats -> registers ----
    float w1[32], wi2[32], w2h[32];
    {
        const float4* p4 = (const float4*)(Whh1 + g * 32);
        #pragma unroll
        for (int i = 0; i < 8; ++i) {
            float4 v = p4[i];
            w1[4*i] = v.x; w1[4*i+1] = v.y; w1[4*i+2] = v.z; w1[4*i+3] = v.w;
        }
    }
    {
        const float4* p4 = (const float4*)(Wih2 + g * 32);
        #pragma unroll
        for (int i = 0; i < 8; ++i) {
            float4 v = p4[i];
            wi2[4*i] = v.x; wi2[4*i+1] = v.y; wi2[4*i+2] = v.z; wi2[4*i+3] = v.w;
        }
    }
    {
        const float4* p4 = (const float4*)(Whh2 + g * 32);
        #pragma unroll
        for (int i = 0; i < 8; ++i) {
            float4 v = p4[i];
            w2h[4*i] = v.x; w2h[4*i+1] = v.y; w2h[4*i+2] = v.z; w2h[4*i+3] = v.w;
        }
    }
    const float bias2 = bih2[g] + bhh2[g];

    // per-lane nonlinearity constants: q==2 is the tanh gate
    const float act_a = (q == 2) ? 2.f : 1.f;
    const float act_b = (q == 2) ? -1.f : 0.f;
    const float nact  = -act_a;

    __syncthreads();

    const float* prow = pre + (size_t)b * T_ * 128 + g;
    float zc = prow[0];
    float zn = prow[128];
    float c1 = 0.f, c2 = 0.f, hsum = 0.f;

#define STEP(P, ZIN)                                                          \
    {                                                                         \
        const float4* h1p = (const float4*)&h1s[P][0];                        \
        float a0 = (ZIN), a1 = 0.f, a2 = 0.f, a3 = 0.f;                       \
        _Pragma("unroll")                                                     \
        for (int i = 0; i < 8; ++i) {                                         \
            float4 v = h1p[i];                                                \
            a0 = fmaf(w1[4*i+0], v.x, a0); a1 = fmaf(w1[4*i+1], v.y, a1);     \
            a2 = fmaf(w1[4*i+2], v.z, a2); a3 = fmaf(w1[4*i+3], v.w, a3);     \
        }                                                                     \
        float z1 = (a0 + a1) + (a2 + a3);                                     \
        float A1 = fmaf(act_a, rcp_(1.f + __expf(nact * z1)), act_b);         \
        float B1 = qperm<0xB1>(A1);                                           \
        float C1 = qperm<0x4E>(A1);                                           \
        float D1 = qperm<0x1B>(A1);                                           \
        c1 = B1 * c1; c1 = fmaf(A1, C1, c1);                                  \
        float th1 = fmaf(2.f, rcp_(1.f + __expf(-2.f * c1)), -1.f);           \
        float h1v = D1 * th1;                                                 \
        if (q0) h1s[1 - (P)][cell] = h1v;                                     \
        __syncthreads();                                                      \
        const float4* h1n = (const float4*)&h1s[1 - (P)][0];                  \
        const float4* h2p = (const float4*)&h2s[P][0];                        \
        float s0 = bias2, s1 = 0.f, s2 = 0.f, s3 = 0.f;                       \
        _Pragma("unroll")                                                     \
        for (int i = 0; i < 8; ++i) {                                         \
            float4 v = h1n[i];                                                \
            s0 = fmaf(wi2[4*i+0], v.x, s0); s1 = fmaf(wi2[4*i+1], v.y, s1);   \
            s2 = fmaf(wi2[4*i+2], v.z, s2); s3 = fmaf(wi2[4*i+3], v.w, s3);   \
        }                                                                     \
        _Pragma("unroll")                                                     \
        for (int i = 0; i < 8; ++i) {                                         \
            float4 v = h2p[i];                                                \
            s0 = fmaf(w2h[4*i+0], v.x, s0); s1 = fmaf(w2h[4*i+1], v.y, s1);   \
            s2 = fmaf(w2h[4*i+2], v.z, s2); s3 = fmaf(w2h[4*i+3], v.w, s3);   \
        }                                                                     \
        float z2 = (s0 + s1) + (s2 + s3);                                     \
        float A2 = fmaf(act_a, rcp_(1.f + __expf(nact * z2)), act_b);         \
        float B2 = qperm<0xB1>(A2);                                           \
        float C2 = qperm<0x4E>(A2);                                           \
        float D2 = qperm<0x1B>(A2);                                           \
        c2 = B2 * c2; c2 = fmaf(A2, C2, c2);                                  \
        float th2 = fmaf(2.f, rcp_(1.f + __expf(-2.f * c2)), -1.f);           \
        float h2v = D2 * th2;                                                 \
        hsum += h2v;                                                          \
        if (q0) h2s[1 - (P)][cell] = h2v;                                     \
    }

    for (int t = 0; t < T_; t += 2) {
        int ta = (t + 2 < T_) ? t + 2 : t;      // uniform clamp (SALU)
        int tb = (t + 3 < T_) ? t + 3 : t;
        float pa = prow[(size_t)ta * 128];      // depth-2 prefetch
        float pb = prow[(size_t)tb * 128];
        STEP(0, zc)
        STEP(1, zn)
        zc = pa;
        zn = pb;
    }
#undef STEP

    // ---- epilogue: pooled = hsum/T ; out = pooled @ fcW^T + fcb ----
    if (q0) pool[cell] = hsum * (1.f / T_);
    __syncthreads();
    if (tid < 2) {
        float acc = fcb[tid];
        #pragma unroll
        for (int j = 0; j < 32; ++j) acc += pool[j] * fcW[tid * 32 + j];
        out[b * 2 + tid] = acc;
    }
}

// ---------------------------------------------------------------------------
extern "C" void kernel_launch(void* const* d_in, const int* in_sizes, int n_in,
                              void* d_out, int out_size, void* d_ws, size_t ws_size,
                              hipStream_t stream)
{
    const float* x    = (const float*)d_in[0];
    const float* gam  = (const float*)d_in[1];
    const float* bet  = (const float*)d_in[2];
    const float* mu   = (const float*)d_in[3];
    const float* var  = (const float*)d_in[4];
    const float* Wih1 = (const float*)d_in[5];
    const float* Whh1 = (const float*)d_in[6];
    const float* bih1 = (const float*)d_in[7];
    const float* bhh1 = (const float*)d_in[8];
    const float* Wih2 = (const float*)d_in[9];
    const float* Whh2 = (const float*)d_in[10];
    const float* bih2 = (const float*)d_in[11];
    const float* bhh2 = (const float*)d_in[12];
    const float* fcW  = (const float*)d_in[13];
    const float* fcb  = (const float*)d_in[14];
    float*       out  = (float*)d_out;

    float* pre = (float*)d_ws;   // B*T*128*4 = 256 MB scratch

    k_bnxw<<<dim3(B_ * T_ / 128), 256, 0, stream>>>(
        x, gam, bet, mu, var, Wih1, bih1, bhh1, pre);
    k_rec<<<dim3(B_), 128, 0, stream>>>(
        pre, Whh1, Wih2, Whh2, bih2, bhh2, fcW, fcb, out);
}